// Round 6
// baseline (568.349 us; speedup 1.0000x reference)
//
#include <hip/hip_runtime.h>
#include <math.h>

#define N_ROWS 16384
#define DMODEL 1024
#define DFF    4096

typedef _Float16 f16;
typedef __attribute__((ext_vector_type(4))) _Float16 f16x4;
typedef __attribute__((ext_vector_type(8))) _Float16 f16x8;
typedef __attribute__((ext_vector_type(16))) float f32x16;

__device__ inline void async_ld16(const f16* g, f16* l) {
  __builtin_amdgcn_global_load_lds(
      (__attribute__((address_space(1))) void*)(g),
      (__attribute__((address_space(3))) void*)(l),
      16, 0, 0);
}

// tanh via hw v_exp_f32 (~5 VALU ops, saturates correctly at +-inf)
__device__ inline float fast_tanh(float x) {
  float t = __expf(2.0f * x);
  return 1.0f - 2.0f / (t + 1.0f);
}

// One kernel casts all three fp32 inputs to f16.
__global__ void cast3_to_f16(const float* __restrict__ a, f16* __restrict__ ah, int na,
                             const float* __restrict__ b, f16* __restrict__ bh, int nb,
                             const float* __restrict__ c, f16* __restrict__ ch, int nc) {
  long i = (long)(blockIdx.x * blockDim.x + threadIdx.x) * 8;
  const float* s; f16* d;
  if (i < na)                { s = a + i;            d = ah + i; }
  else if (i < na + nb)      { s = b + (i - na);     d = bh + (i - na); }
  else if (i < na + nb + nc) { s = c + (i - na - nb); d = ch + (i - na - nb); }
  else return;
  float4 v0 = ((const float4*)s)[0];
  float4 v1 = ((const float4*)s)[1];
  f16x8 h = { (f16)v0.x, (f16)v0.y, (f16)v0.z, (f16)v0.w,
              (f16)v1.x, (f16)v1.y, (f16)v1.z, (f16)v1.w };
  *(f16x8*)d = h;
}

// C[M,Nc] = tanh(A[M,K] @ B[Nc,K]^T + bias) -> f16, fp32 acc.
//
// ROUND 6 RESTRUCTURE. Rounds 1-5 were pinned at the ds_read_b128 ceiling
// (~88 B/cyc/CU, m134): every variant read 4.29 GB from LDS per GEMM and took
// ~190 us. Fix: 256x256 block tile, 4 waves each computing a 128x128 quadrant
// (4x4 accs of 32x32x16) -> each fragment read feeds 4 MFMAs instead of 2:
// LDS read traffic halves, floor moves to MFMA issue (~55 us/GEMM).
// Consequence: 256 acc VGPRs -> 1 wave/SIMD, zero TLP, so latency is hidden
// structurally with double-buffered LDS staging (2 x 32 KB, BK=32): prefetch
// tile k+1 right after the barrier, then ~1024 cyc of MFMA cover the loads.
template <int K>
__global__ __launch_bounds__(256, 1)
void gemm_bt_tanh(const f16* __restrict__ A, const f16* __restrict__ B,
                  const float* __restrict__ bias, f16* __restrict__ C, int Nc) {
  __shared__ __align__(16) f16 As[2][256 * 32];   // 2 x 16 KB
  __shared__ __align__(16) f16 Bs[2][256 * 32];   // 2 x 16 KB  (total 64 KB)

  const int tid  = threadIdx.x;
  const int lane = tid & 63;
  const int wave = tid >> 6;
  const size_t row0 = (size_t)blockIdx.x * 256;
  const size_t col0 = (size_t)blockIdx.y * 256;
  const int wm = (wave >> 1) * 128;   // wave quadrant origin (rows)
  const int wn = (wave & 1) * 128;    // wave quadrant origin (cols)
  const int lr = lane & 31;           // row/col within a 32-tile
  const int h  = lane >> 5;           // k-half of the 16-k step
  const int ke = h * 8;               // element offset of that k-half

  // Staging: 256x32 f16 = 1024 16B-chunks per operand per buffer; 4 loads
  // per thread per operand. Slot sp = l*256+tid -> row sp>>2, chunk sp&3.
  // LDS dest = buf + sp*16B (wave-uniform base + lane-contiguous).
  const f16* Ag[4]; const f16* Bg[4]; int dst[4];
#pragma unroll
  for (int l = 0; l < 4; ++l) {
    const int sp = l * 256 + tid;
    Ag[l] = A + (row0 + (sp >> 2)) * (size_t)K + (sp & 3) * 8;
    Bg[l] = B + (col0 + (sp >> 2)) * (size_t)K + (sp & 3) * 8;
    dst[l] = sp * 8;
  }

  f32x16 acc[4][4] = {};

  // prologue: stage k-tile 0 into buffer 0
#pragma unroll
  for (int l = 0; l < 4; ++l) async_ld16(Ag[l], &As[0][dst[l]]);
#pragma unroll
  for (int l = 0; l < 4; ++l) async_ld16(Bg[l], &Bs[0][dst[l]]);

  const int NIT = K / 32;
  for (int it = 0; it < NIT; ++it) {
    const int b = it & 1;
    // Barrier drains vmcnt(0): buffer b's prefetch (issued a full compute
    // phase ago) is ready; also guarantees everyone is done reading b^1
    // before we overwrite it below.
    __syncthreads();
    if (it + 1 < NIT) {
      const int k0 = (it + 1) * 32;
#pragma unroll
      for (int l = 0; l < 4; ++l) async_ld16(Ag[l] + k0, &As[b ^ 1][dst[l]]);
#pragma unroll
      for (int l = 0; l < 4; ++l) async_ld16(Bg[l] + k0, &Bs[b ^ 1][dst[l]]);
    }
#pragma unroll
    for (int t = 0; t < 2; ++t) {   // two 16-k steps per 32-k tile
      f16x8 af[4], bf[4];
#pragma unroll
      for (int i = 0; i < 4; ++i) {
        af[i] = *(const f16x8*)(&As[b][(wm + i * 32 + lr) * 32 + t * 16 + ke]);
        bf[i] = *(const f16x8*)(&Bs[b][(wn + i * 32 + lr) * 32 + t * 16 + ke]);
      }
#pragma unroll
      for (int i = 0; i < 4; ++i)
#pragma unroll
        for (int j = 0; j < 4; ++j)
          acc[i][j] = __builtin_amdgcn_mfma_f32_32x32x16_f16(af[i], bf[j], acc[i][j], 0, 0, 0);
    }
  }

  // Epilogue. D map: col=lane&31, row=(reg&3)+8*(reg>>2)+4*(lane>>5)
  // [m74/m101-verified].
  const int rbase = 4 * h;
#pragma unroll
  for (int i = 0; i < 4; ++i) {
#pragma unroll
    for (int j = 0; j < 4; ++j) {
      size_t gcol = col0 + wn + j * 32 + lr;
      float bb = bias[gcol];
#pragma unroll
      for (int reg = 0; reg < 16; ++reg) {
        int r = (reg & 3) + 8 * (reg >> 2) + rbase;
        size_t grow = row0 + wm + i * 32 + r;
        C[grow * (size_t)Nc + gcol] = (f16)fast_tanh(acc[i][j][reg] + bb);
      }
    }
  }
}

// out[row] = sigmoid(sum_k wx[row][k] * batch[row][k]); 256 thr/row, fp32 acc
__global__ void rowdot_sigmoid(const f16* __restrict__ wx, const float* __restrict__ batch,
                               float* __restrict__ out) {
  const int row = blockIdx.x;
  const int t = threadIdx.x;
  const f16* wr = wx + (size_t)row * DMODEL + t * 4;
  const float* br = batch + (size_t)row * DMODEL + t * 4;
  f16x4 h = *(const f16x4*)wr;
  float4 b4 = *(const float4*)br;
  float s = (float)h[0] * b4.x + (float)h[1] * b4.y + (float)h[2] * b4.z + (float)h[3] * b4.w;
#pragma unroll
  for (int off = 32; off > 0; off >>= 1) s += __shfl_down(s, off, 64);
  __shared__ float partial[4];
  if ((t & 63) == 0) partial[t >> 6] = s;
  __syncthreads();
  if (t == 0) {
    float tot = partial[0] + partial[1] + partial[2] + partial[3];
    out[row] = 1.0f / (1.0f + __expf(-tot));
  }
}

extern "C" void kernel_launch(void* const* d_in, const int* in_sizes, int n_in,
                              void* d_out, int out_size, void* d_ws, size_t ws_size,
                              hipStream_t stream) {
  const float* batch = (const float*)d_in[0];
  const float* W1    = (const float*)d_in[1];
  const float* b1    = (const float*)d_in[2];
  const float* W2    = (const float*)d_in[3];
  const float* b2    = (const float*)d_in[4];
  float* out = (float*)d_out;

  char* ws = (char*)d_ws;
  f16* batch_h = (f16*)ws;  ws += (size_t)N_ROWS * DMODEL * sizeof(f16);  //  32 MB
  f16* W1_h    = (f16*)ws;  ws += (size_t)DFF * DMODEL * sizeof(f16);     //   8 MB
  f16* W2_h    = (f16*)ws;  ws += (size_t)DMODEL * DFF * sizeof(f16);     //   8 MB
  f16* inner_h = (f16*)ws;  ws += (size_t)N_ROWS * DFF * sizeof(f16);     // 128 MB
  f16* wx_h    = (f16*)ws;  ws += (size_t)N_ROWS * DMODEL * sizeof(f16);  //  32 MB

  const int nb = N_ROWS * DMODEL;   // 16.7M
  const int nw = DFF * DMODEL;      //  4.2M
  const int total8 = (nb + nw + nw) / 8;
  cast3_to_f16<<<total8 / 256, 256, 0, stream>>>(batch, batch_h, nb,
                                                 W1, W1_h, nw, W2, W2_h, nw);

  dim3 g1(N_ROWS / 256, DFF / 256);     // (64, 16) = 1024 blocks
  gemm_bt_tanh<DMODEL><<<g1, 256, 0, stream>>>(batch_h, W1_h, b1, inner_h, DFF);
  dim3 g2(N_ROWS / 256, DMODEL / 256);  // (64, 4) = 256 blocks
  gemm_bt_tanh<DFF><<<g2, 256, 0, stream>>>(inner_h, W2_h, b2, wx_h, DMODEL);

  rowdot_sigmoid<<<N_ROWS, 256, 0, stream>>>(wx_h, batch, out);
}

// Round 7
// 556.019 us; speedup vs baseline: 1.0222x; 1.0222x over previous
//
#include <hip/hip_runtime.h>
#include <math.h>

#define N_ROWS 16384
#define DMODEL 1024
#define DFF    4096

typedef _Float16 f16;
typedef __attribute__((ext_vector_type(4))) _Float16 f16x4;
typedef __attribute__((ext_vector_type(8))) _Float16 f16x8;
typedef __attribute__((ext_vector_type(16))) float f32x16;

__device__ inline void async_ld16(const f16* g, f16* l) {
  __builtin_amdgcn_global_load_lds(
      (__attribute__((address_space(1))) void*)(g),
      (__attribute__((address_space(3))) void*)(l),
      16, 0, 0);
}

// tanh via hw v_exp_f32 (~5 VALU ops, saturates correctly at +-inf)
__device__ inline float fast_tanh(float x) {
  float t = __expf(2.0f * x);
  return 1.0f - 2.0f / (t + 1.0f);
}

// One kernel casts all three fp32 inputs to f16.
__global__ void cast3_to_f16(const float* __restrict__ a, f16* __restrict__ ah, int na,
                             const float* __restrict__ b, f16* __restrict__ bh, int nb,
                             const float* __restrict__ c, f16* __restrict__ ch, int nc) {
  long i = (long)(blockIdx.x * blockDim.x + threadIdx.x) * 8;
  const float* s; f16* d;
  if (i < na)                { s = a + i;            d = ah + i; }
  else if (i < na + nb)      { s = b + (i - na);     d = bh + (i - na); }
  else if (i < na + nb + nc) { s = c + (i - na - nb); d = ch + (i - na - nb); }
  else return;
  float4 v0 = ((const float4*)s)[0];
  float4 v1 = ((const float4*)s)[1];
  f16x8 h = { (f16)v0.x, (f16)v0.y, (f16)v0.z, (f16)v0.w,
              (f16)v1.x, (f16)v1.y, (f16)v1.z, (f16)v1.w };
  *(f16x8*)d = h;
}

// C[M,Nc] = tanh(A[M,K] @ B[Nc,K]^T + bias) -> f16, fp32 acc.
//
// ROUND 7: 256x128 block tile, 4 waves as 2x2 of 128x64 wave tiles
// (acc[4][2] of 32x32x16 = 128 VGPRs). __launch_bounds__(256,2) caps regs at
// 256 -> 2 waves/SIMD, 2 blocks/CU: cross-block barrier decoupling + MFMA
// pipe bubble-filling (the two things whose absence killed round 6), while
// staging traffic/GF is 0.75x of rounds 1-5 (the staging-BW governor).
// Double-buffered LDS (48 KB), single barrier per iter, prefetch issued
// right after the barrier so the whole compute phase covers its latency.
template <int K>
__global__ __launch_bounds__(256, 2)
void gemm_bt_tanh(const f16* __restrict__ A, const f16* __restrict__ B,
                  const float* __restrict__ bias, f16* __restrict__ C, int Nc) {
  __shared__ __align__(16) f16 As[2][256 * 32];   // 2 x 16 KB
  __shared__ __align__(16) f16 Bs[2][128 * 32];   // 2 x  8 KB

  const int tid  = threadIdx.x;
  const int lane = tid & 63;
  const int wave = tid >> 6;
  const size_t row0 = (size_t)blockIdx.x * 256;
  const size_t col0 = (size_t)blockIdx.y * 128;
  const int wm = (wave >> 1) * 128;   // wave row origin (0 or 128)
  const int wn = (wave & 1) * 64;     // wave col origin (0 or 64)
  const int lr = lane & 31;           // row/col within a 32-tile
  const int h  = lane >> 5;           // k-half of the 16-k step
  const int ke = h * 8;

  // Staging. A: 256x32 = 1024 chunks, 4/thread; B: 128x32 = 512, 2/thread.
  // Slot sp -> row sp>>2, chunk sp&3; LDS dest = buf + sp*16B.
  const f16* Ag[4]; const f16* Bg[2]; int dA[4], dB[2];
#pragma unroll
  for (int l = 0; l < 4; ++l) {
    const int sp = l * 256 + tid;
    Ag[l] = A + (row0 + (sp >> 2)) * (size_t)K + (sp & 3) * 8;
    dA[l] = sp * 8;
  }
#pragma unroll
  for (int l = 0; l < 2; ++l) {
    const int sp = l * 256 + tid;
    Bg[l] = B + (col0 + (sp >> 2)) * (size_t)K + (sp & 3) * 8;
    dB[l] = sp * 8;
  }

  f32x16 acc[4][2] = {};

  // prologue: stage k-tile 0 into buffer 0
#pragma unroll
  for (int l = 0; l < 4; ++l) async_ld16(Ag[l], &As[0][dA[l]]);
#pragma unroll
  for (int l = 0; l < 2; ++l) async_ld16(Bg[l], &Bs[0][dB[l]]);

  const int NIT = K / 32;
  for (int it = 0; it < NIT; ++it) {
    const int b = it & 1;
    // Drains buffer b's prefetch (in flight for a full compute phase) and
    // ensures all waves finished reading b^1 before we overwrite it.
    __syncthreads();
    if (it + 1 < NIT) {
      const int k0 = (it + 1) * 32;
#pragma unroll
      for (int l = 0; l < 4; ++l) async_ld16(Ag[l] + k0, &As[b ^ 1][dA[l]]);
#pragma unroll
      for (int l = 0; l < 2; ++l) async_ld16(Bg[l] + k0, &Bs[b ^ 1][dB[l]]);
    }
#pragma unroll
    for (int t = 0; t < 2; ++t) {   // two 16-k steps per 32-k tile
      f16x8 af[4], bf[2];
#pragma unroll
      for (int i = 0; i < 4; ++i)
        af[i] = *(const f16x8*)(&As[b][(wm + i * 32 + lr) * 32 + t * 16 + ke]);
#pragma unroll
      for (int j = 0; j < 2; ++j)
        bf[j] = *(const f16x8*)(&Bs[b][(wn + j * 32 + lr) * 32 + t * 16 + ke]);
#pragma unroll
      for (int i = 0; i < 4; ++i)
#pragma unroll
        for (int j = 0; j < 2; ++j)
          acc[i][j] = __builtin_amdgcn_mfma_f32_32x32x16_f16(af[i], bf[j], acc[i][j], 0, 0, 0);
    }
  }

  // Epilogue. D map: col=lane&31, row=(reg&3)+8*(reg>>2)+4*(lane>>5)
  // [m74/m101-verified].
  const int rbase = 4 * h;
#pragma unroll
  for (int i = 0; i < 4; ++i) {
#pragma unroll
    for (int j = 0; j < 2; ++j) {
      size_t gcol = col0 + wn + j * 32 + lr;
      float bb = bias[gcol];
#pragma unroll
      for (int reg = 0; reg < 16; ++reg) {
        int r = (reg & 3) + 8 * (reg >> 2) + rbase;
        size_t grow = row0 + wm + i * 32 + r;
        C[grow * (size_t)Nc + gcol] = (f16)fast_tanh(acc[i][j][reg] + bb);
      }
    }
  }
}

// out[row] = sigmoid(sum_k wx[row][k] * batch[row][k]); 256 thr/row, fp32 acc
__global__ void rowdot_sigmoid(const f16* __restrict__ wx, const float* __restrict__ batch,
                               float* __restrict__ out) {
  const int row = blockIdx.x;
  const int t = threadIdx.x;
  const f16* wr = wx + (size_t)row * DMODEL + t * 4;
  const float* br = batch + (size_t)row * DMODEL + t * 4;
  f16x4 h = *(const f16x4*)wr;
  float4 b4 = *(const float4*)br;
  float s = (float)h[0] * b4.x + (float)h[1] * b4.y + (float)h[2] * b4.z + (float)h[3] * b4.w;
#pragma unroll
  for (int off = 32; off > 0; off >>= 1) s += __shfl_down(s, off, 64);
  __shared__ float partial[4];
  if ((t & 63) == 0) partial[t >> 6] = s;
  __syncthreads();
  if (t == 0) {
    float tot = partial[0] + partial[1] + partial[2] + partial[3];
    out[row] = 1.0f / (1.0f + __expf(-tot));
  }
}

extern "C" void kernel_launch(void* const* d_in, const int* in_sizes, int n_in,
                              void* d_out, int out_size, void* d_ws, size_t ws_size,
                              hipStream_t stream) {
  const float* batch = (const float*)d_in[0];
  const float* W1    = (const float*)d_in[1];
  const float* b1    = (const float*)d_in[2];
  const float* W2    = (const float*)d_in[3];
  const float* b2    = (const float*)d_in[4];
  float* out = (float*)d_out;

  char* ws = (char*)d_ws;
  f16* batch_h = (f16*)ws;  ws += (size_t)N_ROWS * DMODEL * sizeof(f16);  //  32 MB
  f16* W1_h    = (f16*)ws;  ws += (size_t)DFF * DMODEL * sizeof(f16);     //   8 MB
  f16* W2_h    = (f16*)ws;  ws += (size_t)DMODEL * DFF * sizeof(f16);     //   8 MB
  f16* inner_h = (f16*)ws;  ws += (size_t)N_ROWS * DFF * sizeof(f16);     // 128 MB
  f16* wx_h    = (f16*)ws;  ws += (size_t)N_ROWS * DMODEL * sizeof(f16);  //  32 MB

  const int nb = N_ROWS * DMODEL;   // 16.7M
  const int nw = DFF * DMODEL;      //  4.2M
  const int total8 = (nb + nw + nw) / 8;
  cast3_to_f16<<<total8 / 256, 256, 0, stream>>>(batch, batch_h, nb,
                                                 W1, W1_h, nw, W2, W2_h, nw);

  dim3 g1(N_ROWS / 256, DFF / 128);     // (64, 32) = 2048 blocks, 4 exact gens
  gemm_bt_tanh<DMODEL><<<g1, 256, 0, stream>>>(batch_h, W1_h, b1, inner_h, DFF);
  dim3 g2(N_ROWS / 256, DMODEL / 128);  // (64, 8) = 512 blocks, 1 exact gen
  gemm_bt_tanh<DFF><<<g2, 256, 0, stream>>>(inner_h, W2_h, b2, wx_h, DMODEL);

  rowdot_sigmoid<<<N_ROWS, 256, 0, stream>>>(wx_h, batch, out);
}

// Round 8
// 471.123 us; speedup vs baseline: 1.2064x; 1.1802x over previous
//
#include <hip/hip_runtime.h>
#include <math.h>

#define N_ROWS 16384
#define DMODEL 1024
#define DFF    4096

typedef _Float16 f16;
typedef __attribute__((ext_vector_type(4))) _Float16 f16x4;
typedef __attribute__((ext_vector_type(8))) _Float16 f16x8;
typedef __attribute__((ext_vector_type(4))) float f32x4;

__device__ inline void async_ld16(const f16* g, f16* l) {
  __builtin_amdgcn_global_load_lds(
      (__attribute__((address_space(1))) void*)(g),
      (__attribute__((address_space(3))) void*)(l),
      16, 0, 0);
}

// tanh via hw v_exp_f32 (~5 VALU ops, saturates correctly at +-inf)
__device__ inline float fast_tanh(float x) {
  float t = __expf(2.0f * x);
  return 1.0f - 2.0f / (t + 1.0f);
}

// One kernel casts all three fp32 inputs to f16.
__global__ void cast3_to_f16(const float* __restrict__ a, f16* __restrict__ ah, int na,
                             const float* __restrict__ b, f16* __restrict__ bh, int nb,
                             const float* __restrict__ c, f16* __restrict__ ch, int nc) {
  long i = (long)(blockIdx.x * blockDim.x + threadIdx.x) * 8;
  const float* s; f16* d;
  if (i < na)                { s = a + i;            d = ah + i; }
  else if (i < na + nb)      { s = b + (i - na);     d = bh + (i - na); }
  else if (i < na + nb + nc) { s = c + (i - na - nb); d = ch + (i - na - nb); }
  else return;
  float4 v0 = ((const float4*)s)[0];
  float4 v1 = ((const float4*)s)[1];
  f16x8 h = { (f16)v0.x, (f16)v0.y, (f16)v0.z, (f16)v0.w,
              (f16)v1.x, (f16)v1.y, (f16)v1.z, (f16)v1.w };
  *(f16x8*)d = h;
}

// C[M,Nc] = tanh(A[M,K] @ B[Nc,K]^T + bias) -> f16, fp32 acc.
//
// ROUND 8: the measured family-optimum structure (R1: 128x128 tile, BK=32,
// 16 KB x2 LDS, 16x16x32 MFMA, 2-barrier K-loop, width-16 global_load_lds,
// NO swizzle) — every departure tried (BK=64, 32x32 MFMA, swizzles, dbuf,
// bigger tiles) measured equal or worse (R3-R7). Two retained deltas:
// fast_tanh epilogue (R3 win) and __launch_bounds__(256,4): this kernel is
// 56 arch-VGPR + 64 AGPR = 120/wave and 16 KB LDS, so 4 blocks/CU fit
// exactly (480<=512 regs/SIMD, 64 KB LDS). That makes GEMM2's 1024-block
// grid exactly ONE resident generation (zero tail; at 3/CU its makespan was
// ~1.5x ideal) and GEMM1's 4096 blocks exactly 4 generations, plus more TLP
// for the 2-barrier overlap.
template <int K>
__global__ __launch_bounds__(256, 4)
void gemm_bt_tanh(const f16* __restrict__ A, const f16* __restrict__ B,
                  const float* __restrict__ bias, f16* __restrict__ C, int Nc) {
  __shared__ __align__(16) f16 As[128 * 32];
  __shared__ __align__(16) f16 Bs[128 * 32];

  const int tid  = threadIdx.x;
  const int lane = tid & 63;
  const int wave = tid >> 6;
  const size_t row0 = (size_t)blockIdx.x * 128;
  const size_t col0 = (size_t)blockIdx.y * 128;
  const int wm = (wave >> 1) * 64;
  const int wn = (wave & 1) * 64;
  const int fr = lane & 15;
  const int fk = (lane >> 4) * 8;

  // staging: thread t loads row t/4, 16B chunk t%4 (rows 0-63; +64*K for 64-127)
  const int srow   = tid >> 2;
  const int schunk = (tid & 3) * 8;
  const f16* Ap = A + (row0 + srow) * (size_t)K + schunk;
  const f16* Bp = B + (col0 + srow) * (size_t)K + schunk;
  f16* Asd = As + tid * 8;
  f16* Bsd = Bs + tid * 8;

  f32x4 acc[4][4] = {};

  for (int k0 = 0; k0 < K; k0 += 32) {
    __syncthreads();  // all waves done reading LDS from previous iter
    async_ld16(Ap + k0, Asd);
    async_ld16(Ap + (size_t)64 * K + k0, Asd + 2048);
    async_ld16(Bp + k0, Bsd);
    async_ld16(Bp + (size_t)64 * K + k0, Bsd + 2048);
    __syncthreads();  // drains vmcnt(0): staged tiles visible

    f16x8 af[4], bf[4];
#pragma unroll
    for (int i = 0; i < 4; ++i) {
      af[i] = *(const f16x8*)(As + (wm + i * 16 + fr) * 32 + fk);
      bf[i] = *(const f16x8*)(Bs + (wn + i * 16 + fr) * 32 + fk);
    }
#pragma unroll
    for (int i = 0; i < 4; ++i)
#pragma unroll
      for (int j = 0; j < 4; ++j)
        acc[i][j] = __builtin_amdgcn_mfma_f32_16x16x32_f16(af[i], bf[j], acc[i][j], 0, 0, 0);
  }

  // epilogue: C/D map col=lane&15, row=(lane>>4)*4+reg  [m89-verified]
  const int erow = wm + (lane >> 4) * 4;
  const int ecol = wn + fr;
#pragma unroll
  for (int i = 0; i < 4; ++i) {
#pragma unroll
    for (int j = 0; j < 4; ++j) {
      size_t gcol = col0 + ecol + j * 16;
      float b = bias[gcol];
#pragma unroll
      for (int r = 0; r < 4; ++r) {
        size_t grow = row0 + erow + i * 16 + r;
        C[grow * (size_t)Nc + gcol] = (f16)fast_tanh(acc[i][j][r] + b);
      }
    }
  }
}

// out[row] = sigmoid(sum_k wx[row][k] * batch[row][k]); 256 thr/row, fp32 acc
__global__ void rowdot_sigmoid(const f16* __restrict__ wx, const float* __restrict__ batch,
                               float* __restrict__ out) {
  const int row = blockIdx.x;
  const int t = threadIdx.x;
  const f16* wr = wx + (size_t)row * DMODEL + t * 4;
  const float* br = batch + (size_t)row * DMODEL + t * 4;
  f16x4 h = *(const f16x4*)wr;
  float4 b4 = *(const float4*)br;
  float s = (float)h[0] * b4.x + (float)h[1] * b4.y + (float)h[2] * b4.z + (float)h[3] * b4.w;
#pragma unroll
  for (int off = 32; off > 0; off >>= 1) s += __shfl_down(s, off, 64);
  __shared__ float partial[4];
  if ((t & 63) == 0) partial[t >> 6] = s;
  __syncthreads();
  if (t == 0) {
    float tot = partial[0] + partial[1] + partial[2] + partial[3];
    out[row] = 1.0f / (1.0f + __expf(-tot));
  }
}

extern "C" void kernel_launch(void* const* d_in, const int* in_sizes, int n_in,
                              void* d_out, int out_size, void* d_ws, size_t ws_size,
                              hipStream_t stream) {
  const float* batch = (const float*)d_in[0];
  const float* W1    = (const float*)d_in[1];
  const float* b1    = (const float*)d_in[2];
  const float* W2    = (const float*)d_in[3];
  const float* b2    = (const float*)d_in[4];
  float* out = (float*)d_out;

  char* ws = (char*)d_ws;
  f16* batch_h = (f16*)ws;  ws += (size_t)N_ROWS * DMODEL * sizeof(f16);  //  32 MB
  f16* W1_h    = (f16*)ws;  ws += (size_t)DFF * DMODEL * sizeof(f16);     //   8 MB
  f16* W2_h    = (f16*)ws;  ws += (size_t)DMODEL * DFF * sizeof(f16);     //   8 MB
  f16* inner_h = (f16*)ws;  ws += (size_t)N_ROWS * DFF * sizeof(f16);     // 128 MB
  f16* wx_h    = (f16*)ws;  ws += (size_t)N_ROWS * DMODEL * sizeof(f16);  //  32 MB

  const int nb = N_ROWS * DMODEL;   // 16.7M
  const int nw = DFF * DMODEL;      //  4.2M
  const int total8 = (nb + nw + nw) / 8;
  cast3_to_f16<<<total8 / 256, 256, 0, stream>>>(batch, batch_h, nb,
                                                 W1, W1_h, nw, W2, W2_h, nw);

  dim3 g1(N_ROWS / 128, DFF / 128);     // (128, 32) = 4096 blocks = 4 gens @4/CU
  gemm_bt_tanh<DMODEL><<<g1, 256, 0, stream>>>(batch_h, W1_h, b1, inner_h, DFF);
  dim3 g2(N_ROWS / 128, DMODEL / 128);  // (128, 8) = 1024 blocks = 1 gen @4/CU
  gemm_bt_tanh<DFF><<<g2, 256, 0, stream>>>(inner_h, W2_h, b2, wx_h, DMODEL);

  rowdot_sigmoid<<<N_ROWS, 256, 0, stream>>>(wx_h, batch, out);
}